// Round 1
// baseline (8464.218 us; speedup 1.0000x reference)
//
#include <hip/hip_runtime.h>
#include <hip/hip_bf16.h>

#define GQ 16
#define L_IN 4096
#define T_UP 8192
#define CB 1024
#define D_CB 8
#define NB 4

// ---------------- weight repacks ----------------
// W_up: [ci=1024][co=1024][kk=4] (IOH) -> Wr[kk][ci][co]
__global__ __launch_bounds__(256) void repack_up(const float* __restrict__ Wup,
                                                 float* __restrict__ Wr) {
    int idx = blockIdx.x * 256 + threadIdx.x;            // 4*1024*1024 total
    int kk  = idx >> 20;
    int rem = idx & ((1 << 20) - 1);
    int ci  = rem >> 10;
    int co  = rem & 1023;
    Wr[idx] = Wup[((ci << 10) + co) * 4 + kk];
}

// W_head: [o=512][ci=1024][kk=7] (OIH) -> Wr[kk][ci][o]
__global__ __launch_bounds__(256) void repack_head(const float* __restrict__ Wh,
                                                   float* __restrict__ Wr) {
    int idx = blockIdx.x * 256 + threadIdx.x;            // 7*1024*512 total
    int kk  = idx / (1024 * 512);
    int rem = idx - kk * (1024 * 512);
    int ci  = rem >> 9;
    int o   = rem & 511;
    Wr[idx] = Wh[(o * 1024 + ci) * 7 + kk];
}

// ---------------- dequant + project ----------------
// z[b][l][c], c = g*512+e
__global__ __launch_bounds__(256) void dequant_project(
    const int* __restrict__ indices, const float* __restrict__ codebooks,
    const float* __restrict__ scales, const float* __restrict__ Wout,
    const float* __restrict__ bout, float* __restrict__ z)
{
    __shared__ float w_lds[8192];
    __shared__ float b_lds[1024];
    __shared__ float part[128];
    __shared__ float summed[16];
    int tid = threadIdx.x;
    for (int k = tid; k < 8192; k += 256) w_lds[k] = Wout[k];
    for (int k = tid; k < 1024; k += 256) b_lds[k] = bout[k];
    int p0 = blockIdx.x * 16;          // 16 positions per block
    int b  = p0 >> 12;
    int l0 = p0 & 4095;
    __syncthreads();
    for (int i = 0; i < 16; ++i) {
        int l = l0 + i;
        if (tid < 128) {
            int gq = tid >> 3;         // 0..15
            int d  = tid & 7;
            int idx = indices[(b * GQ + gq) * L_IN + l];
            float v = 0.f;
            if (idx >= 0) {
                int ic = (idx < CB) ? idx : 0;
                v = codebooks[(gq * CB + ic) * D_CB + d] * scales[gq * D_CB + d];
            }
            part[tid] = v;
        }
        __syncthreads();
        if (tid < 16) {
            int g = tid >> 3, d = tid & 7;
            float s = 0.f;
            for (int q = 0; q < 8; ++q) s += part[(g * 8 + q) * 8 + d];
            summed[tid] = s;
        }
        __syncthreads();
        #pragma unroll
        for (int j = 0; j < 4; ++j) {
            int c = tid + j * 256;
            int g = c >> 9;
            float acc = b_lds[c];
            #pragma unroll
            for (int d = 0; d < 8; ++d)
                acc += summed[g * 8 + d] * w_lds[(g * 8 + d) * 512 + (c & 511)];
            z[(size_t)(p0 + i) * 1024 + c] = acc;
        }
        __syncthreads();
    }
}

// ---------------- conv transpose (k=4, s=2, SAME) ----------------
// even t=2m: zu[t] = z[m-1]*W[0] + z[m]*W[2] ; odd t=2m+1: z[m]*W[1] + z[m+1]*W[3]
// zu[b][t][co]
__global__ __launch_bounds__(256) void conv_up(
    const float* __restrict__ z, const float* __restrict__ Wr,
    const float* __restrict__ bup, float* __restrict__ zu)
{
    __shared__ float A[32 * 33];          // [ci][row], 33 rows staged
    __shared__ float Bs[2 * 32 * 128];    // [tap][ci][co]
    int tid = threadIdx.x;
    int co0 = blockIdx.x * 128;
    int m0  = blockIdx.y * 32;
    int bz  = blockIdx.z;
    int b = bz >> 1, P = bz & 1;          // parity
    int tx = tid & 31, ty = tid >> 5;
    float acc[4][4] = {};
    int lbase = m0 - 1 + P;
    for (int c0 = 0; c0 < 1024; c0 += 32) {
        for (int f = tid; f < 33 * 32; f += 256) {
            int row = f >> 5, ci = f & 31;
            int l = lbase + row;
            float v = 0.f;
            if (l >= 0 && l < L_IN) v = z[(size_t)(b * L_IN + l) * 1024 + c0 + ci];
            A[ci * 33 + row] = v;
        }
        for (int f = tid; f < 2 * 32 * 128; f += 256) {
            int tap = f >> 12;
            int rem = f & 4095;
            int ci = rem >> 7, co = rem & 127;
            Bs[f] = Wr[(size_t)(P + 2 * tap) * (1024 * 1024) + (c0 + ci) * 1024 + co0 + co];
        }
        __syncthreads();
        for (int ci = 0; ci < 32; ++ci) {
            float a[5];
            #pragma unroll
            for (int jj = 0; jj < 5; ++jj) a[jj] = A[ci * 33 + ty * 4 + jj];
            float b0[4], b1[4];
            #pragma unroll
            for (int i = 0; i < 4; ++i) {
                b0[i] = Bs[ci * 128 + tx * 4 + i];
                b1[i] = Bs[4096 + ci * 128 + tx * 4 + i];
            }
            #pragma unroll
            for (int j = 0; j < 4; ++j)
                #pragma unroll
                for (int i = 0; i < 4; ++i)
                    acc[j][i] += a[j] * b0[i] + a[j + 1] * b1[i];
        }
        __syncthreads();
    }
    #pragma unroll
    for (int j = 0; j < 4; ++j) {
        int m = m0 + ty * 4 + j;
        int t = 2 * m + P;
        float4 v = make_float4(acc[j][0] + bup[co0 + tx * 4 + 0],
                               acc[j][1] + bup[co0 + tx * 4 + 1],
                               acc[j][2] + bup[co0 + tx * 4 + 2],
                               acc[j][3] + bup[co0 + tx * 4 + 3]);
        *(float4*)&zu[(size_t)(b * T_UP + t) * 1024 + co0 + tx * 4] = v;
    }
}

// ---------------- head conv (k=7, SAME) ----------------
// out[b][o][t] (NCH)
__global__ __launch_bounds__(256) void conv_head(
    const float* __restrict__ zu, const float* __restrict__ Wr,
    const float* __restrict__ bh, float* __restrict__ out)
{
    __shared__ float A[32 * 135];        // [ci][row], 134 rows staged (pitch 135)
    __shared__ float Bs[7 * 32 * 32];    // [kk][ci][o]
    int tid = threadIdx.x;
    int o0 = blockIdx.x * 32;
    int t0 = blockIdx.y * 128;
    int b  = blockIdx.z;
    int tx = tid & 31, ty = tid >> 5;
    int tl = tx * 4;
    float acc[4][4] = {};                // [o][t]
    for (int c0 = 0; c0 < 1024; c0 += 32) {
        for (int f = tid; f < 134 * 32; f += 256) {
            int row = f >> 5, ci = f & 31;
            int l = t0 - 3 + row;
            float v = 0.f;
            if (l >= 0 && l < T_UP) v = zu[(size_t)(b * T_UP + l) * 1024 + c0 + ci];
            A[ci * 135 + row] = v;
        }
        for (int f = tid; f < 7 * 32 * 32; f += 256) {
            int kk = f >> 10;
            int rem = f & 1023;
            int ci = rem >> 5, o = rem & 31;
            Bs[f] = Wr[(size_t)kk * (1024 * 512) + (c0 + ci) * 512 + o0 + o];
        }
        __syncthreads();
        for (int ci = 0; ci < 32; ++ci) {
            float a[10];
            #pragma unroll
            for (int r = 0; r < 10; ++r) a[r] = A[ci * 135 + tl + r];
            #pragma unroll
            for (int kk = 0; kk < 7; ++kk) {
                float bv[4];
                #pragma unroll
                for (int i = 0; i < 4; ++i) bv[i] = Bs[kk * 1024 + ci * 32 + ty * 4 + i];
                #pragma unroll
                for (int i = 0; i < 4; ++i)
                    #pragma unroll
                    for (int j = 0; j < 4; ++j)
                        acc[i][j] += a[kk + j] * bv[i];
            }
        }
        __syncthreads();
    }
    #pragma unroll
    for (int i = 0; i < 4; ++i) {
        int o = o0 + ty * 4 + i;
        float bb = bh[o];
        float4 v = make_float4(acc[i][0] + bb, acc[i][1] + bb, acc[i][2] + bb, acc[i][3] + bb);
        *(float4*)&out[(size_t)(b * 512 + o) * T_UP + t0 + tl] = v;
    }
}

extern "C" void kernel_launch(void* const* d_in, const int* in_sizes, int n_in,
                              void* d_out, int out_size, void* d_ws, size_t ws_size,
                              hipStream_t stream) {
    const int*   indices   = (const int*)d_in[0];
    const float* codebooks = (const float*)d_in[1];
    const float* scales    = (const float*)d_in[2];
    const float* Wout      = (const float*)d_in[3];
    const float* bout      = (const float*)d_in[4];
    const float* Wup       = (const float*)d_in[5];
    const float* bup       = (const float*)d_in[6];
    const float* Wh        = (const float*)d_in[7];
    const float* bh        = (const float*)d_in[8];
    float* out = (float*)d_out;

    float* ws    = (float*)d_ws;
    float* z     = ws;                      // 4*4096*1024 = 16,777,216 f32
    float* zu    = z + 16777216;            // 4*8192*1024 = 33,554,432 f32
    float* Wr_up = zu + 33554432;           // 4*1024*1024 = 4,194,304 f32
    float* Wr_h  = Wr_up + 4194304;         // 7*1024*512  = 3,670,016 f32

    repack_up   <<<dim3(16384), dim3(256), 0, stream>>>(Wup, Wr_up);
    repack_head <<<dim3(14336), dim3(256), 0, stream>>>(Wh, Wr_h);
    dequant_project<<<dim3(1024), dim3(256), 0, stream>>>(indices, codebooks, scales,
                                                          Wout, bout, z);
    conv_up  <<<dim3(8, 128, 8), dim3(256), 0, stream>>>(z, Wr_up, bup, zu);
    conv_head<<<dim3(16, 64, 4), dim3(256), 0, stream>>>(zu, Wr_h, bh, out);
}

// Round 2
// 516.031 us; speedup vs baseline: 16.4025x; 16.4025x over previous
//
#include <hip/hip_runtime.h>
#include <hip/hip_bf16.h>

typedef __attribute__((ext_vector_type(8))) short bf16x8;
typedef __attribute__((ext_vector_type(4))) float f32x4;

#define GQ 16
#define L_IN 4096
#define T_UP 8192
#define CB 1024
#define ZROWS 4098   // 4096 + 1 pad each side
#define UROWS 8198   // 8192 + 3 pad each side

__device__ __forceinline__ void gload16(const void* g, void* l) {
    __builtin_amdgcn_global_load_lds((const __attribute__((address_space(1))) void*)g,
                                     (__attribute__((address_space(3))) void*)l, 16, 0, 0);
}

// ---------------- zero pad rows (ws is poisoned each call) ----------------
__global__ __launch_bounds__(256) void zero_pads(__hip_bfloat16* __restrict__ zp,
                                                 __hip_bfloat16* __restrict__ zup) {
    int idx = blockIdx.x * 256 + threadIdx.x;
    if (idx < 8192) {                       // z pads: rows 0, ZROWS-1 per batch
        int b = idx >> 11, rs = (idx >> 10) & 1, c = idx & 1023;
        size_t row = (size_t)b * ZROWS + (rs ? (ZROWS - 1) : 0);
        zp[row * 1024 + c] = __float2bfloat16(0.f);
    } else if (idx < 8192 + 24576) {        // zu pads: rows 0..2, UROWS-3..UROWS-1
        int rem = idx - 8192;
        int b = rem / 6144, r2 = rem % 6144;
        int r6 = r2 >> 10, c = r2 & 1023;
        size_t row = (size_t)b * UROWS + (r6 < 3 ? r6 : (UROWS - 6 + r6));
        zup[row * 1024 + c] = __float2bfloat16(0.f);
    }
}

// ---------------- weight repacks (fp32 -> bf16) ----------------
// W_up IOH [ci][co][kk=4] -> Wr[kk][co][ci] bf16
__global__ __launch_bounds__(256) void repack_up(const float* __restrict__ Wup,
                                                 __hip_bfloat16* __restrict__ Wr) {
    int idx = blockIdx.x * 256 + threadIdx.x;           // 4*1024*1024
    int kk = idx >> 20;
    int co = (idx >> 10) & 1023;
    int ci = idx & 1023;
    Wr[idx] = __float2bfloat16(Wup[((ci << 10) + co) * 4 + kk]);
}

// W_head OIH [o=512][ci][kk=7] -> Wr[kk][o][ci] bf16
__global__ __launch_bounds__(256) void repack_head(const float* __restrict__ Wh,
                                                   __hip_bfloat16* __restrict__ Wr) {
    int idx = blockIdx.x * 256 + threadIdx.x;           // 7*512*1024
    int kk = idx >> 19;
    int rem = idx & ((1 << 19) - 1);
    int o = rem >> 10;
    int ci = rem & 1023;
    Wr[idx] = __float2bfloat16(Wh[(o * 1024 + ci) * 7 + kk]);
}

// ---------------- dequant + project -> z bf16 (padded rows) ----------------
__global__ __launch_bounds__(256) void dequant_project(
    const int* __restrict__ indices, const float* __restrict__ codebooks,
    const float* __restrict__ scales, const float* __restrict__ Wout,
    const float* __restrict__ bout, __hip_bfloat16* __restrict__ z)
{
    __shared__ float w_lds[8192];
    __shared__ float b_lds[1024];
    __shared__ float part[128];
    __shared__ float summed[16];
    int tid = threadIdx.x;
    for (int k = tid; k < 8192; k += 256) w_lds[k] = Wout[k];
    for (int k = tid; k < 1024; k += 256) b_lds[k] = bout[k];
    int p0 = blockIdx.x * 16;
    int b  = p0 >> 12;
    int l0 = p0 & 4095;
    __syncthreads();
    for (int i = 0; i < 16; ++i) {
        int l = l0 + i;
        if (tid < 128) {
            int gq = tid >> 3;
            int d  = tid & 7;
            int idx = indices[(b * GQ + gq) * L_IN + l];
            float v = 0.f;
            if (idx >= 0) {
                int ic = (idx < CB) ? idx : 0;
                v = codebooks[(gq * CB + ic) * 8 + d] * scales[gq * 8 + d];
            }
            part[tid] = v;
        }
        __syncthreads();
        if (tid < 16) {
            int g = tid >> 3, d = tid & 7;
            float s = 0.f;
            for (int q = 0; q < 8; ++q) s += part[(g * 8 + q) * 8 + d];
            summed[tid] = s;
        }
        __syncthreads();
        #pragma unroll
        for (int j = 0; j < 4; ++j) {
            int c = tid + j * 256;
            int g = c >> 9;
            float acc = b_lds[c];
            #pragma unroll
            for (int d = 0; d < 8; ++d)
                acc += summed[g * 8 + d] * w_lds[(g * 8 + d) * 512 + (c & 511)];
            z[((size_t)b * ZROWS + l + 1) * 1024 + c] = __float2bfloat16(acc);
        }
        __syncthreads();
    }
}

// ---------------- conv transpose via MFMA ----------------
// out t=2m+P; P=0 taps{0,2} rows{m-1,m}; P=1 taps{1,3} rows{m,m+1}
// A panel: padded z rows [m0+P, m0+P+128] (129 rows), tap j reads staged row mrel+j
__global__ __launch_bounds__(256) void conv_up_mfma(
    const __hip_bfloat16* __restrict__ zp, const __hip_bfloat16* __restrict__ Wr,
    const float* __restrict__ bup, __hip_bfloat16* __restrict__ zup)
{
    __shared__ __hip_bfloat16 Asm[144 * 32];
    __shared__ __hip_bfloat16 Bsm[2 * 128 * 32];
    const int tid = threadIdx.x;
    const int lane = tid & 63;
    const int w = tid >> 6;
    const int co0 = blockIdx.x * 128;
    const int m0 = blockIdx.y * 128;
    const int b = blockIdx.z >> 1, P = blockIdx.z & 1;
    const int wm = w >> 1, wn = w & 1;

    const __hip_bfloat16* zbase = zp + ((size_t)b * ZROWS + m0 + P) * 1024;
    const __hip_bfloat16* wbase = Wr + (size_t)P * (1024 * 1024);

    const f32x4 zero4 = {0.f, 0.f, 0.f, 0.f};
    f32x4 acc[4][4];
#pragma unroll
    for (int r = 0; r < 4; ++r)
#pragma unroll
        for (int c = 0; c < 4; ++c) acc[r][c] = zero4;

    const int l15 = lane & 15;
    const int kq = lane >> 4;       // 16B chunk selector (k-chunk)

    for (int c0 = 0; c0 < 1024; c0 += 32) {
        // ---- stage A: 516 chunks of 16B, swizzled source (ciq ^= (row>>1)&3) ----
#pragma unroll
        for (int it = 0; it < 3; ++it) {
            int chunk = it * 256 + tid;
            if (chunk < 516) {
                int row = chunk >> 2, cq = chunk & 3;
                int csrc = cq ^ ((row >> 1) & 3);
                gload16(zbase + (size_t)row * 1024 + c0 + csrc * 8,
                        (char*)Asm + ((it * 256 + (w << 6)) << 4));
            }
        }
        // ---- stage B: 2 taps x 128 co x 32 ci = 1024 chunks ----
#pragma unroll
        for (int it = 0; it < 4; ++it) {
            int chunk = it * 256 + tid;
            int tap = chunk >> 9, rem = chunk & 511;
            int co = rem >> 2, cq = rem & 3;
            int csrc = cq ^ ((co >> 1) & 3);
            gload16(wbase + ((size_t)(tap * 2048 + co0 + co)) * 1024 + c0 + csrc * 8,
                    (char*)Bsm + ((it * 256 + (w << 6)) << 4));
        }
        __syncthreads();

        bf16x8 af[2][4], bfr[2][4];
#pragma unroll
        for (int j = 0; j < 2; ++j)
#pragma unroll
            for (int r = 0; r < 4; ++r) {
                int row = (wm << 6) + r * 16 + l15 + j;
                int pq = kq ^ ((row >> 1) & 3);
                af[j][r] = *(const bf16x8*)&Asm[row * 32 + pq * 8];
            }
#pragma unroll
        for (int j = 0; j < 2; ++j)
#pragma unroll
            for (int c = 0; c < 4; ++c) {
                int row = (wn << 6) + c * 16 + l15;
                int pq = kq ^ ((row >> 1) & 3);
                bfr[j][c] = *(const bf16x8*)&Bsm[j * 4096 + row * 32 + pq * 8];
            }
#pragma unroll
        for (int j = 0; j < 2; ++j)
#pragma unroll
            for (int r = 0; r < 4; ++r)
#pragma unroll
                for (int c = 0; c < 4; ++c)
                    acc[r][c] = __builtin_amdgcn_mfma_f32_16x16x32_bf16(
                        af[j][r], bfr[j][c], acc[r][c], 0, 0, 0);
        __syncthreads();
    }

    const int mrow = (wm << 6) + (kq << 2);
    const int cob = co0 + (wn << 6) + l15;
#pragma unroll
    for (int c = 0; c < 4; ++c) {
        float bias = bup[cob + c * 16];
#pragma unroll
        for (int r = 0; r < 4; ++r)
#pragma unroll
            for (int e = 0; e < 4; ++e) {
                int m = m0 + mrow + r * 16 + e;
                zup[((size_t)b * UROWS + 3 + P + 2 * m) * 1024 + cob + c * 16] =
                    __float2bfloat16(acc[r][c][e] + bias);
            }
    }
}

// ---------------- head conv via MFMA (A=W so output t is lane&15 -> coalesced) ----
// A panel: padded zu rows [t0, t0+133] (134 rows), tap kk reads staged row trel+kk
__global__ __launch_bounds__(256) void conv_head_mfma(
    const __hip_bfloat16* __restrict__ zup, const __hip_bfloat16* __restrict__ Wr,
    const float* __restrict__ bh, float* __restrict__ out)
{
    __shared__ __hip_bfloat16 Asm[144 * 32];
    __shared__ __hip_bfloat16 Bsm[7 * 64 * 32];
    const int tid = threadIdx.x;
    const int lane = tid & 63;
    const int w = tid >> 6;
    const int o0 = blockIdx.x * 64;
    const int t0 = blockIdx.y * 128;
    const int b = blockIdx.z;
    const int wm = w >> 1, wn = w & 1;

    const __hip_bfloat16* zbase = zup + ((size_t)b * UROWS + t0) * 1024;

    const f32x4 zero4 = {0.f, 0.f, 0.f, 0.f};
    f32x4 acc[2][4];
#pragma unroll
    for (int c = 0; c < 2; ++c)
#pragma unroll
        for (int r = 0; r < 4; ++r) acc[c][r] = zero4;

    const int l15 = lane & 15;
    const int kq = lane >> 4;

    for (int c0 = 0; c0 < 1024; c0 += 32) {
        // ---- stage A: 134 rows = 536 chunks ----
#pragma unroll
        for (int it = 0; it < 3; ++it) {
            int chunk = it * 256 + tid;
            if (chunk < 536) {
                int row = chunk >> 2, cq = chunk & 3;
                int csrc = cq ^ ((row >> 1) & 3);
                gload16(zbase + (size_t)row * 1024 + c0 + csrc * 8,
                        (char*)Asm + ((it * 256 + (w << 6)) << 4));
            }
        }
        // ---- stage B: 7 taps x 64 o x 32 ci = 1792 chunks ----
#pragma unroll
        for (int it = 0; it < 7; ++it) {
            int chunk = it * 256 + tid;
            int kk = chunk >> 8, rem = chunk & 255;
            int o = rem >> 2, cq = rem & 3;
            int csrc = cq ^ ((o >> 1) & 3);
            gload16(Wr + ((size_t)(kk * 512 + o0 + o)) * 1024 + c0 + csrc * 8,
                    (char*)Bsm + ((it * 256 + (w << 6)) << 4));
        }
        __syncthreads();

#pragma unroll
        for (int kk = 0; kk < 7; ++kk) {
            bf16x8 wf[2], zf[4];
#pragma unroll
            for (int c = 0; c < 2; ++c) {
                int orow = (wn << 5) + c * 16 + l15;
                int pq = kq ^ ((orow >> 1) & 3);
                wf[c] = *(const bf16x8*)&Bsm[(kk * 64 + orow) * 32 + pq * 8];
            }
#pragma unroll
            for (int r = 0; r < 4; ++r) {
                int row = (wm << 6) + r * 16 + l15 + kk;
                int pq = kq ^ ((row >> 1) & 3);
                zf[r] = *(const bf16x8*)&Asm[row * 32 + pq * 8];
            }
#pragma unroll
            for (int c = 0; c < 2; ++c)
#pragma unroll
                for (int r = 0; r < 4; ++r)
                    acc[c][r] = __builtin_amdgcn_mfma_f32_16x16x32_bf16(
                        wf[c], zf[r], acc[c][r], 0, 0, 0);
        }
        __syncthreads();
    }

    const int ob = o0 + (wn << 5) + (kq << 2);
    const int tb = t0 + (wm << 6) + l15;
#pragma unroll
    for (int c = 0; c < 2; ++c)
#pragma unroll
        for (int e = 0; e < 4; ++e) {
            int o = ob + c * 16 + e;
            float bias = bh[o];
#pragma unroll
            for (int r = 0; r < 4; ++r)
                out[((size_t)b * 512 + o) * T_UP + tb + r * 16] = acc[c][r][e] + bias;
        }
}

extern "C" void kernel_launch(void* const* d_in, const int* in_sizes, int n_in,
                              void* d_out, int out_size, void* d_ws, size_t ws_size,
                              hipStream_t stream) {
    const int*   indices   = (const int*)d_in[0];
    const float* codebooks = (const float*)d_in[1];
    const float* scales    = (const float*)d_in[2];
    const float* Wout      = (const float*)d_in[3];
    const float* bout      = (const float*)d_in[4];
    const float* Wup       = (const float*)d_in[5];
    const float* bup       = (const float*)d_in[6];
    const float* Wh        = (const float*)d_in[7];
    const float* bh        = (const float*)d_in[8];
    float* out = (float*)d_out;

    __hip_bfloat16* zp    = (__hip_bfloat16*)d_ws;
    __hip_bfloat16* zup   = zp + (size_t)4 * ZROWS * 1024;     // 16,785,408
    __hip_bfloat16* wr_up = zup + (size_t)4 * UROWS * 1024;    // +33,579,008
    __hip_bfloat16* wr_h  = wr_up + (size_t)4 * 1024 * 1024;   // +4,194,304

    zero_pads  <<<dim3(128),   dim3(256), 0, stream>>>(zp, zup);
    repack_up  <<<dim3(16384), dim3(256), 0, stream>>>(Wup, wr_up);
    repack_head<<<dim3(14336), dim3(256), 0, stream>>>(Wh, wr_h);
    dequant_project<<<dim3(1024), dim3(256), 0, stream>>>(indices, codebooks, scales,
                                                          Wout, bout, zp);
    conv_up_mfma  <<<dim3(8, 32, 8), dim3(256), 0, stream>>>(zp, wr_up, bup, zup);
    conv_head_mfma<<<dim3(8, 64, 4), dim3(256), 0, stream>>>(zup, wr_h, bh, out);
}

// Round 3
// 513.970 us; speedup vs baseline: 16.4683x; 1.0040x over previous
//
#include <hip/hip_runtime.h>
#include <hip/hip_bf16.h>

typedef __attribute__((ext_vector_type(8))) short bf16x8;
typedef __attribute__((ext_vector_type(4))) float f32x4;

#define GQ 16
#define L_IN 4096
#define T_UP 8192
#define CB 1024
#define ZROWS 4098   // 4096 + 1 pad each side
#define UROWS 8198   // 8192 + 3 pad each side

__device__ __forceinline__ void gload16(const void* g, void* l) {
    __builtin_amdgcn_global_load_lds((const __attribute__((address_space(1))) void*)g,
                                     (__attribute__((address_space(3))) void*)l, 16, 0, 0);
}

// ---------------- zero pad rows ----------------
__global__ __launch_bounds__(256) void zero_pads(__hip_bfloat16* __restrict__ zp,
                                                 __hip_bfloat16* __restrict__ zup) {
    int idx = blockIdx.x * 256 + threadIdx.x;
    if (idx < 8192) {
        int b = idx >> 11, rs = (idx >> 10) & 1, c = idx & 1023;
        size_t row = (size_t)b * ZROWS + (rs ? (ZROWS - 1) : 0);
        zp[row * 1024 + c] = __float2bfloat16(0.f);
    } else if (idx < 8192 + 24576) {
        int rem = idx - 8192;
        int b = rem / 6144, r2 = rem % 6144;
        int r6 = r2 >> 10, c = r2 & 1023;
        size_t row = (size_t)b * UROWS + (r6 < 3 ? r6 : (UROWS - 6 + r6));
        zup[row * 1024 + c] = __float2bfloat16(0.f);
    }
}

// ---------------- weight repacks (fp32 -> bf16) ----------------
// W_up IOH [ci][co][kk=4] -> Wr[kk][co][ci] bf16
__global__ __launch_bounds__(256) void repack_up(const float* __restrict__ Wup,
                                                 __hip_bfloat16* __restrict__ Wr) {
    int idx = blockIdx.x * 256 + threadIdx.x;
    int kk = idx >> 20;
    int co = (idx >> 10) & 1023;
    int ci = idx & 1023;
    Wr[idx] = __float2bfloat16(Wup[((ci << 10) + co) * 4 + kk]);
}

// W_head OIH [o=512][ci][kk=7] -> Wr[kk][o][ci] bf16
__global__ __launch_bounds__(256) void repack_head(const float* __restrict__ Wh,
                                                   __hip_bfloat16* __restrict__ Wr) {
    int idx = blockIdx.x * 256 + threadIdx.x;
    int kk = idx >> 19;
    int rem = idx & ((1 << 19) - 1);
    int o = rem >> 10;
    int ci = rem & 1023;
    Wr[idx] = __float2bfloat16(Wh[(o * 1024 + ci) * 7 + kk]);
}

// ---------------- dequant + project -> z bf16 (padded rows) ----------------
__global__ __launch_bounds__(256) void dequant_project(
    const int* __restrict__ indices, const float* __restrict__ codebooks,
    const float* __restrict__ scales, const float* __restrict__ Wout,
    const float* __restrict__ bout, __hip_bfloat16* __restrict__ z)
{
    __shared__ float w_lds[8192];
    __shared__ float b_lds[1024];
    __shared__ float part[128];
    __shared__ float summed[16];
    int tid = threadIdx.x;
    for (int k = tid; k < 8192; k += 256) w_lds[k] = Wout[k];
    for (int k = tid; k < 1024; k += 256) b_lds[k] = bout[k];
    int p0 = blockIdx.x * 16;
    int b  = p0 >> 12;
    int l0 = p0 & 4095;
    __syncthreads();
    for (int i = 0; i < 16; ++i) {
        int l = l0 + i;
        if (tid < 128) {
            int gq = tid >> 3;
            int d  = tid & 7;
            int idx = indices[(b * GQ + gq) * L_IN + l];
            float v = 0.f;
            if (idx >= 0) {
                int ic = (idx < CB) ? idx : 0;
                v = codebooks[(gq * CB + ic) * 8 + d] * scales[gq * 8 + d];
            }
            part[tid] = v;
        }
        __syncthreads();
        if (tid < 16) {
            int g = tid >> 3, d = tid & 7;
            float s = 0.f;
            for (int q = 0; q < 8; ++q) s += part[(g * 8 + q) * 8 + d];
            summed[tid] = s;
        }
        __syncthreads();
        #pragma unroll
        for (int j = 0; j < 4; ++j) {
            int c = tid + j * 256;
            int g = c >> 9;
            float acc = b_lds[c];
            #pragma unroll
            for (int d = 0; d < 8; ++d)
                acc += summed[g * 8 + d] * w_lds[(g * 8 + d) * 512 + (c & 511)];
            z[((size_t)b * ZROWS + l + 1) * 1024 + c] = __float2bfloat16(acc);
        }
        __syncthreads();
    }
}

// ======= conv transpose: K_eff = 2*1024 (tap-linearized), 128m x 128co block =======
// t = 2m+P. P=0: taps{0,2} read z rows {m-1,m}; P=1: taps{1,3} read {m,m+1}.
// Padded-row slab base for (P,j): m0 + P + j.
__global__ __launch_bounds__(256, 2) void conv_up_mfma(
    const __hip_bfloat16* __restrict__ zp, const __hip_bfloat16* __restrict__ Wr,
    const float* __restrict__ bup, __hip_bfloat16* __restrict__ zup)
{
    __shared__ __hip_bfloat16 Als[2][128][64];
    __shared__ __hip_bfloat16 Bls[2][128][64];
    const int tid = threadIdx.x;
    const int lane = tid & 63;
    const int w = tid >> 6;
    const int wm = w >> 1, wn = w & 1;
    const int l15 = lane & 15, kq = lane >> 4;
    const int m0  = blockIdx.x * 128;
    const int co0 = blockIdx.y * 128;
    const int b = blockIdx.z >> 1, P = blockIdx.z & 1;

    const __hip_bfloat16* zb = zp + ((size_t)b * ZROWS + m0 + P) * 1024;
    const __hip_bfloat16* wb = Wr + ((size_t)P * 1024 + co0) * 1024;

    auto stage = [&](int buf, int s) {
        int j = s & 1, ci0 = (s >> 1) << 6;
        const __hip_bfloat16* sa = zb + (size_t)j * 1024 + ci0;           // z rows +j
        const __hip_bfloat16* sb = wb + (size_t)j * 2048 * 1024 + ci0;    // tap kk=P+2j
        #pragma unroll
        for (int it = 0; it < 4; ++it) {
            int chunk = it * 256 + tid;
            int row = chunk >> 3, cs = chunk & 7;
            int cq = cs ^ (row & 7);
            gload16(sa + (size_t)row * 1024 + cq * 8,
                    (char*)&Als[buf][0][0] + ((it * 256 + (w << 6)) << 4));
            gload16(sb + (size_t)row * 1024 + cq * 8,
                    (char*)&Bls[buf][0][0] + ((it * 256 + (w << 6)) << 4));
        }
    };

    const f32x4 zero4 = {0.f, 0.f, 0.f, 0.f};
    f32x4 acc[4][4];
    #pragma unroll
    for (int r = 0; r < 4; ++r)
        #pragma unroll
        for (int c = 0; c < 4; ++c) acc[r][c] = zero4;

    stage(0, 0);
    __syncthreads();
    int cur = 0;
    for (int s = 0; s < 32; ++s) {
        if (s + 1 < 32) stage(cur ^ 1, s + 1);
        bf16x8 af[2][4], bfr[2][4];
        #pragma unroll
        for (int sl = 0; sl < 2; ++sl) {
            #pragma unroll
            for (int r = 0; r < 4; ++r) {
                int row = (wm << 6) + r * 16 + l15;
                int pc = (sl * 4 + kq) ^ (row & 7);
                af[sl][r] = *(const bf16x8*)&Als[cur][row][pc * 8];
            }
            #pragma unroll
            for (int c = 0; c < 4; ++c) {
                int row = (wn << 6) + c * 16 + l15;
                int pc = (sl * 4 + kq) ^ (row & 7);
                bfr[sl][c] = *(const bf16x8*)&Bls[cur][row][pc * 8];
            }
        }
        __builtin_amdgcn_s_setprio(1);
        #pragma unroll
        for (int sl = 0; sl < 2; ++sl)
            #pragma unroll
            for (int r = 0; r < 4; ++r)
                #pragma unroll
                for (int c = 0; c < 4; ++c)
                    acc[r][c] = __builtin_amdgcn_mfma_f32_16x16x32_bf16(
                        af[sl][r], bfr[sl][c], acc[r][c], 0, 0, 0);
        __builtin_amdgcn_s_setprio(0);
        __syncthreads();
        cur ^= 1;
    }

    const int mb  = m0 + (wm << 6) + (kq << 2);
    const int cob = co0 + (wn << 6) + l15;
    #pragma unroll
    for (int c = 0; c < 4; ++c) {
        float bias = bup[cob + c * 16];
        #pragma unroll
        for (int r = 0; r < 4; ++r)
            #pragma unroll
            for (int e = 0; e < 4; ++e) {
                int m = mb + r * 16 + e;
                zup[((size_t)b * UROWS + 3 + P + 2 * m) * 1024 + cob + c * 16] =
                    __float2bfloat16(acc[r][c][e] + bias);
            }
    }
}

// ======= head conv: K_eff = 7*1024, 128o x 128t block, A=W (o), B=zu (t) =======
// out[t] = sum_kk W[kk] . zu_pad[t+kk]
__global__ __launch_bounds__(256, 2) void conv_head_mfma(
    const __hip_bfloat16* __restrict__ zup, const __hip_bfloat16* __restrict__ Wr,
    const float* __restrict__ bh, float* __restrict__ out)
{
    __shared__ __hip_bfloat16 Als[2][128][64];
    __shared__ __hip_bfloat16 Bls[2][128][64];
    const int tid = threadIdx.x;
    const int lane = tid & 63;
    const int w = tid >> 6;
    const int wm = w >> 1, wn = w & 1;
    const int l15 = lane & 15, kq = lane >> 4;
    const int t0 = blockIdx.x * 128;
    const int o0 = blockIdx.y * 128;
    const int b  = blockIdx.z;

    const __hip_bfloat16* wb = Wr + (size_t)o0 * 1024;
    const __hip_bfloat16* zb = zup + ((size_t)b * UROWS + t0) * 1024;

    auto stage = [&](int buf, int kk, int ci0) {
        const __hip_bfloat16* sa = wb + (size_t)kk * 512 * 1024 + ci0;  // W rows o
        const __hip_bfloat16* sb = zb + (size_t)kk * 1024 + ci0;        // zu rows t0+kk
        #pragma unroll
        for (int it = 0; it < 4; ++it) {
            int chunk = it * 256 + tid;
            int row = chunk >> 3, cs = chunk & 7;
            int cq = cs ^ (row & 7);
            gload16(sa + (size_t)row * 1024 + cq * 8,
                    (char*)&Als[buf][0][0] + ((it * 256 + (w << 6)) << 4));
            gload16(sb + (size_t)row * 1024 + cq * 8,
                    (char*)&Bls[buf][0][0] + ((it * 256 + (w << 6)) << 4));
        }
    };

    const f32x4 zero4 = {0.f, 0.f, 0.f, 0.f};
    f32x4 acc[4][4];
    #pragma unroll
    for (int r = 0; r < 4; ++r)
        #pragma unroll
        for (int c = 0; c < 4; ++c) acc[r][c] = zero4;

    int nk = 0, nc = 0;            // (kk, ci0) of the NEXT step to stage
    stage(0, nk, nc);
    if (++nk == 7) { nk = 0; nc += 64; }
    __syncthreads();
    int cur = 0;
    for (int s = 0; s < 112; ++s) {
        if (s + 1 < 112) {
            stage(cur ^ 1, nk, nc);
            if (++nk == 7) { nk = 0; nc += 64; }
        }
        bf16x8 af[2][4], bfr[2][4];
        #pragma unroll
        for (int sl = 0; sl < 2; ++sl) {
            #pragma unroll
            for (int r = 0; r < 4; ++r) {
                int row = (wm << 6) + r * 16 + l15;
                int pc = (sl * 4 + kq) ^ (row & 7);
                af[sl][r] = *(const bf16x8*)&Als[cur][row][pc * 8];
            }
            #pragma unroll
            for (int c = 0; c < 4; ++c) {
                int row = (wn << 6) + c * 16 + l15;
                int pc = (sl * 4 + kq) ^ (row & 7);
                bfr[sl][c] = *(const bf16x8*)&Bls[cur][row][pc * 8];
            }
        }
        __builtin_amdgcn_s_setprio(1);
        #pragma unroll
        for (int sl = 0; sl < 2; ++sl)
            #pragma unroll
            for (int r = 0; r < 4; ++r)
                #pragma unroll
                for (int c = 0; c < 4; ++c)
                    acc[r][c] = __builtin_amdgcn_mfma_f32_16x16x32_bf16(
                        af[sl][r], bfr[sl][c], acc[r][c], 0, 0, 0);
        __builtin_amdgcn_s_setprio(0);
        __syncthreads();
        cur ^= 1;
    }

    const int ob = o0 + (wm << 6) + (kq << 2);
    const int tb = t0 + (wn << 6) + l15;
    #pragma unroll
    for (int r = 0; r < 4; ++r)
        #pragma unroll
        for (int e = 0; e < 4; ++e) {
            int o = ob + r * 16 + e;
            float bias = bh[o];
            #pragma unroll
            for (int c = 0; c < 4; ++c)
                out[((size_t)b * 512 + o) * T_UP + tb + c * 16] = acc[r][c][e] + bias;
        }
}

extern "C" void kernel_launch(void* const* d_in, const int* in_sizes, int n_in,
                              void* d_out, int out_size, void* d_ws, size_t ws_size,
                              hipStream_t stream) {
    const int*   indices   = (const int*)d_in[0];
    const float* codebooks = (const float*)d_in[1];
    const float* scales    = (const float*)d_in[2];
    const float* Wout      = (const float*)d_in[3];
    const float* bout      = (const float*)d_in[4];
    const float* Wup       = (const float*)d_in[5];
    const float* bup       = (const float*)d_in[6];
    const float* Wh        = (const float*)d_in[7];
    const float* bh        = (const float*)d_in[8];
    float* out = (float*)d_out;

    __hip_bfloat16* zp    = (__hip_bfloat16*)d_ws;
    __hip_bfloat16* zup   = zp + (size_t)4 * ZROWS * 1024;
    __hip_bfloat16* wr_up = zup + (size_t)4 * UROWS * 1024;
    __hip_bfloat16* wr_h  = wr_up + (size_t)4 * 1024 * 1024;

    zero_pads  <<<dim3(128),   dim3(256), 0, stream>>>(zp, zup);
    repack_up  <<<dim3(16384), dim3(256), 0, stream>>>(Wup, wr_up);
    repack_head<<<dim3(14336), dim3(256), 0, stream>>>(Wh, wr_h);
    dequant_project<<<dim3(1024), dim3(256), 0, stream>>>(indices, codebooks, scales,
                                                          Wout, bout, zp);
    conv_up_mfma  <<<dim3(32, 8, 8), dim3(256), 0, stream>>>(zp, wr_up, bup, zup);
    conv_head_mfma<<<dim3(64, 4, 4), dim3(256), 0, stream>>>(zup, wr_h, bh, out);
}

// Round 5
// 466.625 us; speedup vs baseline: 18.1392x; 1.1015x over previous
//
#include <hip/hip_runtime.h>
#include <hip/hip_bf16.h>

typedef __attribute__((ext_vector_type(8))) short bf16x8;
typedef __attribute__((ext_vector_type(4))) float f32x4;

#define GQ 16
#define L_IN 4096
#define T_UP 8192
#define CB 1024
#define ZROWS 4098   // 4096 + 1 pad each side
#define UROWS 8198   // 8192 + 3 pad each side

__device__ __forceinline__ void gload16(const void* g, void* l) {
    __builtin_amdgcn_global_load_lds((const __attribute__((address_space(1))) void*)g,
                                     (__attribute__((address_space(3))) void*)l, 16, 0, 0);
}

#define SB()  __builtin_amdgcn_s_barrier()
#define LGKM() do { asm volatile("s_waitcnt lgkmcnt(0)" ::: "memory"); \
                    __builtin_amdgcn_sched_barrier(0); } while (0)
#define VMW(n) do { __builtin_amdgcn_sched_barrier(0); \
                    asm volatile("s_waitcnt vmcnt(" #n ")" ::: "memory"); \
                    __builtin_amdgcn_sched_barrier(0); } while (0)

// 16 MFMA: quadrant (MH, NH) of the wave's 128x64 C tile, K=64 (2 slices)
#define MM(MH, NH) do {                                                          \
    __builtin_amdgcn_s_setprio(1);                                               \
    _Pragma("unroll") for (int j_ = 0; j_ < 4; ++j_)                             \
      _Pragma("unroll") for (int n_ = 0; n_ < 2; ++n_)                           \
        _Pragma("unroll") for (int s_ = 0; s_ < 2; ++s_)                         \
          acc[(MH)*4 + j_][(NH)*2 + n_] = __builtin_amdgcn_mfma_f32_16x16x32_bf16( \
              af[j_][s_], bq[(NH)*2 + n_][s_], acc[(MH)*4 + j_][(NH)*2 + n_],    \
              0, 0, 0);                                                          \
    __builtin_amdgcn_s_setprio(0);                                               \
} while (0)

// ---------------- zero pad rows ----------------
__global__ __launch_bounds__(256) void zero_pads(__hip_bfloat16* __restrict__ zp,
                                                 __hip_bfloat16* __restrict__ zup) {
    int idx = blockIdx.x * 256 + threadIdx.x;
    if (idx < 8192) {
        int b = idx >> 11, rs = (idx >> 10) & 1, c = idx & 1023;
        size_t row = (size_t)b * ZROWS + (rs ? (ZROWS - 1) : 0);
        zp[row * 1024 + c] = __float2bfloat16(0.f);
    } else if (idx < 8192 + 24576) {
        int rem = idx - 8192;
        int b = rem / 6144, r2 = rem % 6144;
        int r6 = r2 >> 10, c = r2 & 1023;
        size_t row = (size_t)b * UROWS + (r6 < 3 ? r6 : (UROWS - 6 + r6));
        zup[row * 1024 + c] = __float2bfloat16(0.f);
    }
}

// ---------------- weight repacks (fp32 -> bf16) ----------------
__global__ __launch_bounds__(256) void repack_up(const float* __restrict__ Wup,
                                                 __hip_bfloat16* __restrict__ Wr) {
    int idx = blockIdx.x * 256 + threadIdx.x;
    int kk = idx >> 20;
    int co = (idx >> 10) & 1023;
    int ci = idx & 1023;
    Wr[idx] = __float2bfloat16(Wup[((ci << 10) + co) * 4 + kk]);
}

__global__ __launch_bounds__(256) void repack_head(const float* __restrict__ Wh,
                                                   __hip_bfloat16* __restrict__ Wr) {
    int idx = blockIdx.x * 256 + threadIdx.x;
    int kk = idx >> 19;
    int rem = idx & ((1 << 19) - 1);
    int o = rem >> 10;
    int ci = rem & 1023;
    Wr[idx] = __float2bfloat16(Wh[(o * 1024 + ci) * 7 + kk]);
}

// ---------------- dequant + project -> z bf16 (padded rows) ----------------
__global__ __launch_bounds__(256) void dequant_project(
    const int* __restrict__ indices, const float* __restrict__ codebooks,
    const float* __restrict__ scales, const float* __restrict__ Wout,
    const float* __restrict__ bout, __hip_bfloat16* __restrict__ z)
{
    __shared__ float w_lds[8192];
    __shared__ float b_lds[1024];
    __shared__ float part[128];
    __shared__ float summed[16];
    int tid = threadIdx.x;
    for (int k = tid; k < 8192; k += 256) w_lds[k] = Wout[k];
    for (int k = tid; k < 1024; k += 256) b_lds[k] = bout[k];
    int p0 = blockIdx.x * 16;
    int b  = p0 >> 12;
    int l0 = p0 & 4095;
    __syncthreads();
    for (int i = 0; i < 16; ++i) {
        int l = l0 + i;
        if (tid < 128) {
            int gq = tid >> 3;
            int d  = tid & 7;
            int idx = indices[(b * GQ + gq) * L_IN + l];
            float v = 0.f;
            if (idx >= 0) {
                int ic = (idx < CB) ? idx : 0;
                v = codebooks[(gq * CB + ic) * 8 + d] * scales[gq * 8 + d];
            }
            part[tid] = v;
        }
        __syncthreads();
        if (tid < 16) {
            int g = tid >> 3, d = tid & 7;
            float s = 0.f;
            for (int q = 0; q < 8; ++q) s += part[(g * 8 + q) * 8 + d];
            summed[tid] = s;
        }
        __syncthreads();
        #pragma unroll
        for (int j = 0; j < 4; ++j) {
            int c = tid + j * 256;
            int g = c >> 9;
            float acc = b_lds[c];
            #pragma unroll
            for (int d = 0; d < 8; ++d)
                acc += summed[g * 8 + d] * w_lds[(g * 8 + d) * 512 + (c & 511)];
            z[((size_t)b * ZROWS + l + 1) * 1024 + c] = __float2bfloat16(acc);
        }
        __syncthreads();
    }
}

// ================= 8-phase 256x256 tile conv kernels =================
// parts: 0 = A rows 0-127, 1 = A rows 128-255, 2 = B rows 0-127, 3 = B rows 128-255
// stage order per iteration it (tiles 2it, 2it+1 consumed):
//   ph1:(2it+1,1) ph2:(2it+2,2) ph3:(2it+2,3) ph4:(2it+2,0)
//   ph5:(2it+2,1) ph6:(2it+3,2) ph7:(2it+3,3) ph8:(2it+3,0)
// gates: vmcnt(6) at ph4/ph8; LAST iteration ph4 uses vmcnt(0) (stages skipped
// beyond NT would otherwise leave needed loads uncounted).

// ---- conv transpose: A = z (m), B = Wr_up (co), K = 2*1024 ----
__global__ __launch_bounds__(512, 2) void conv_up_mfma(
    const __hip_bfloat16* __restrict__ zp, const __hip_bfloat16* __restrict__ Wr,
    const float* __restrict__ bup, __hip_bfloat16* __restrict__ zup)
{
    __shared__ __hip_bfloat16 Als[2][256][64];
    __shared__ __hip_bfloat16 Bls[2][256][64];
    const int tid = threadIdx.x;
    const int lane = tid & 63;
    const int w = tid >> 6;
    const int wm = w >> 2, wn = w & 3;
    const int l15 = lane & 15, kq = lane >> 4;
    const int m0  = blockIdx.x * 256;
    const int co0 = blockIdx.y * 256;
    const int b = blockIdx.z >> 1, P = blockIdx.z & 1;
    const int NT = 32, NIT = 16;

    const __hip_bfloat16* abase = zp + ((size_t)b * ZROWS + m0 + P) * 1024;
    const __hip_bfloat16* bbase = Wr + ((size_t)P * 1024 + co0) * 1024;

    auto stage = [&](int kt, int part) {
        if (kt >= NT) return;
        const int buf = kt & 1;
        const int j = kt >> 4, ci0 = (kt & 15) << 6;
        const int rb = (part & 1) << 7;
        const __hip_bfloat16* src;
        __hip_bfloat16* dst;
        if (part < 2) { src = abase + ((size_t)j + rb) * 1024 + ci0;
                        dst = &Als[buf][rb][0]; }
        else          { src = bbase + ((size_t)j * 2048 + rb) * 1024 + ci0;
                        dst = &Bls[buf][rb][0]; }
        #pragma unroll
        for (int it = 0; it < 2; ++it) {
            int chunk = it * 512 + tid;
            int row = chunk >> 3, cs = chunk & 7;
            int cq = cs ^ (row & 7);
            gload16(src + (size_t)row * 1024 + cq * 8,
                    (char*)dst + ((it * 512 + (w << 6)) << 4));
        }
    };

    f32x4 acc[8][4];
    const f32x4 z4 = {0.f, 0.f, 0.f, 0.f};
    #pragma unroll
    for (int i = 0; i < 8; ++i)
        #pragma unroll
        for (int j = 0; j < 4; ++j) acc[i][j] = z4;

    bf16x8 af[4][2], bq[4][2];

    auto rdA = [&](int buf, int mh) {
        #pragma unroll
        for (int j = 0; j < 4; ++j)
            #pragma unroll
            for (int sl = 0; sl < 2; ++sl) {
                int row = (wm << 7) + (mh << 6) + j * 16 + l15;
                int ch = (sl * 4 + kq) ^ (row & 7);
                af[j][sl] = *(const bf16x8*)&Als[buf][row][ch * 8];
            }
    };
    auto rdB = [&](int buf) {
        #pragma unroll
        for (int nf = 0; nf < 4; ++nf)
            #pragma unroll
            for (int sl = 0; sl < 2; ++sl) {
                int row = (wn << 6) + nf * 16 + l15;
                int ch = (sl * 4 + kq) ^ (row & 7);
                bq[nf][sl] = *(const bf16x8*)&Bls[buf][row][ch * 8];
            }
    };

    // prologue: tile0 (B-lo,B-hi,A-lo,A-hi), tile1 (B-lo,B-hi,A-lo)
    stage(0, 2); stage(0, 3); stage(0, 0); stage(0, 1);
    stage(1, 2); stage(1, 3); stage(1, 0);
    VMW(6);
    SB();

    for (int it = 0; it < NIT; ++it) {
        const bool lastit = (it == NIT - 1);
        // ph1
        rdA(0, 0); rdB(0);
        stage(2 * it + 1, 1);
        SB(); LGKM(); MM(0, 0); SB();
        // ph2
        stage(2 * it + 2, 2);
        SB(); MM(0, 1); SB();
        // ph3
        rdA(0, 1);
        stage(2 * it + 2, 3);
        SB(); LGKM(); MM(1, 1); SB();
        // ph4
        stage(2 * it + 2, 0);
        if (lastit) { VMW(0); } else { VMW(6); }
        SB(); MM(1, 0); SB();
        // ph5
        rdA(1, 0); rdB(1);
        stage(2 * it + 2, 1);
        SB(); LGKM(); MM(0, 0); SB();
        // ph6
        stage(2 * it + 3, 2);
        SB(); MM(0, 1); SB();
        // ph7
        rdA(1, 1);
        stage(2 * it + 3, 3);
        SB(); LGKM(); MM(1, 1); SB();
        // ph8
        stage(2 * it + 3, 0);
        if (!lastit) { VMW(6); }
        SB(); MM(1, 0); SB();
    }

    float bias[4];
    #pragma unroll
    for (int nf = 0; nf < 4; ++nf) bias[nf] = bup[co0 + (wn << 6) + nf * 16 + l15];
    const int mbase = m0 + (wm << 7) + (kq << 2);
    const int cob = co0 + (wn << 6) + l15;
    #pragma unroll
    for (int mf = 0; mf < 8; ++mf)
        #pragma unroll
        for (int e = 0; e < 4; ++e) {
            int m = mbase + mf * 16 + e;
            size_t rowoff = ((size_t)b * UROWS + 3 + P + 2 * m) * 1024;
            #pragma unroll
            for (int nf = 0; nf < 4; ++nf)
                zup[rowoff + cob + nf * 16] = __float2bfloat16(acc[mf][nf][e] + bias[nf]);
        }
}

// ---- head conv: A = Wr_h (o), B = zu (t), K = 7*1024 ----
__global__ __launch_bounds__(512, 2) void conv_head_mfma(
    const __hip_bfloat16* __restrict__ zup, const __hip_bfloat16* __restrict__ Wr,
    const float* __restrict__ bh, float* __restrict__ out)
{
    __shared__ __hip_bfloat16 Als[2][256][64];
    __shared__ __hip_bfloat16 Bls[2][256][64];
    const int tid = threadIdx.x;
    const int lane = tid & 63;
    const int w = tid >> 6;
    const int wm = w >> 2, wn = w & 3;
    const int l15 = lane & 15, kq = lane >> 4;
    const int t0 = blockIdx.x * 256;
    const int o0 = blockIdx.y * 256;
    const int b  = blockIdx.z;
    const int NT = 112, NIT = 56;

    const __hip_bfloat16* bbase = zup + ((size_t)b * UROWS + t0) * 1024;

    auto stage = [&](int kt, int part) {
        if (kt >= NT) return;
        const int buf = kt & 1;
        const int kk = kt >> 4, ci0 = (kt & 15) << 6;
        const int rb = (part & 1) << 7;
        const __hip_bfloat16* src;
        __hip_bfloat16* dst;
        if (part < 2) { src = Wr + ((size_t)(kk * 512 + o0 + rb)) * 1024 + ci0;
                        dst = &Als[buf][rb][0]; }
        else          { src = bbase + ((size_t)(kk + rb)) * 1024 + ci0;
                        dst = &Bls[buf][rb][0]; }
        #pragma unroll
        for (int it = 0; it < 2; ++it) {
            int chunk = it * 512 + tid;
            int row = chunk >> 3, cs = chunk & 7;
            int cq = cs ^ (row & 7);
            gload16(src + (size_t)row * 1024 + cq * 8,
                    (char*)dst + ((it * 512 + (w << 6)) << 4));
        }
    };

    f32x4 acc[8][4];
    const f32x4 z4 = {0.f, 0.f, 0.f, 0.f};
    #pragma unroll
    for (int i = 0; i < 8; ++i)
        #pragma unroll
        for (int j = 0; j < 4; ++j) acc[i][j] = z4;

    bf16x8 af[4][2], bq[4][2];

    auto rdA = [&](int buf, int mh) {
        #pragma unroll
        for (int j = 0; j < 4; ++j)
            #pragma unroll
            for (int sl = 0; sl < 2; ++sl) {
                int row = (wm << 7) + (mh << 6) + j * 16 + l15;
                int ch = (sl * 4 + kq) ^ (row & 7);
                af[j][sl] = *(const bf16x8*)&Als[buf][row][ch * 8];
            }
    };
    auto rdB = [&](int buf) {
        #pragma unroll
        for (int nf = 0; nf < 4; ++nf)
            #pragma unroll
            for (int sl = 0; sl < 2; ++sl) {
                int row = (wn << 6) + nf * 16 + l15;
                int ch = (sl * 4 + kq) ^ (row & 7);
                bq[nf][sl] = *(const bf16x8*)&Bls[buf][row][ch * 8];
            }
    };

    stage(0, 2); stage(0, 3); stage(0, 0); stage(0, 1);
    stage(1, 2); stage(1, 3); stage(1, 0);
    VMW(6);
    SB();

    for (int it = 0; it < NIT; ++it) {
        const bool lastit = (it == NIT - 1);
        // ph1
        rdA(0, 0); rdB(0);
        stage(2 * it + 1, 1);
        SB(); LGKM(); MM(0, 0); SB();
        // ph2
        stage(2 * it + 2, 2);
        SB(); MM(0, 1); SB();
        // ph3
        rdA(0, 1);
        stage(2 * it + 2, 3);
        SB(); LGKM(); MM(1, 1); SB();
        // ph4
        stage(2 * it + 2, 0);
        if (lastit) { VMW(0); } else { VMW(6); }
        SB(); MM(1, 0); SB();
        // ph5
        rdA(1, 0); rdB(1);
        stage(2 * it + 2, 1);
        SB(); LGKM(); MM(0, 0); SB();
        // ph6
        stage(2 * it + 3, 2);
        SB(); MM(0, 1); SB();
        // ph7
        rdA(1, 1);
        stage(2 * it + 3, 3);
        SB(); LGKM(); MM(1, 1); SB();
        // ph8
        stage(2 * it + 3, 0);
        if (!lastit) { VMW(6); }
        SB(); MM(1, 0); SB();
    }

    const int obase = o0 + (wm << 7) + (kq << 2);
    const int tbase = t0 + (wn << 6) + l15;
    #pragma unroll
    for (int mf = 0; mf < 8; ++mf)
        #pragma unroll
        for (int e = 0; e < 4; ++e) {
            int o = obase + mf * 16 + e;
            float bias = bh[o];
            size_t rowoff = ((size_t)b * 512 + o) * T_UP + tbase;
            #pragma unroll
            for (int nf = 0; nf < 4; ++nf)
                out[rowoff + nf * 16] = acc[mf][nf][e] + bias;
        }
}

extern "C" void kernel_launch(void* const* d_in, const int* in_sizes, int n_in,
                              void* d_out, int out_size, void* d_ws, size_t ws_size,
                              hipStream_t stream) {
    const int*   indices   = (const int*)d_in[0];
    const float* codebooks = (const float*)d_in[1];
    const float* scales    = (const float*)d_in[2];
    const float* Wout      = (const float*)d_in[3];
    const float* bout      = (const float*)d_in[4];
    const float* Wup       = (const float*)d_in[5];
    const float* bup       = (const float*)d_in[6];
    const float* Wh        = (const float*)d_in[7];
    const float* bh        = (const float*)d_in[8];
    float* out = (float*)d_out;

    __hip_bfloat16* zp    = (__hip_bfloat16*)d_ws;
    __hip_bfloat16* zup   = zp + (size_t)4 * ZROWS * 1024;
    __hip_bfloat16* wr_up = zup + (size_t)4 * UROWS * 1024;
    __hip_bfloat16* wr_h  = wr_up + (size_t)4 * 1024 * 1024;

    zero_pads  <<<dim3(128),   dim3(256), 0, stream>>>(zp, zup);
    repack_up  <<<dim3(16384), dim3(256), 0, stream>>>(Wup, wr_up);
    repack_head<<<dim3(14336), dim3(256), 0, stream>>>(Wh, wr_h);
    dequant_project<<<dim3(1024), dim3(256), 0, stream>>>(indices, codebooks, scales,
                                                          Wout, bout, zp);
    conv_up_mfma  <<<dim3(16, 4, 8), dim3(512), 0, stream>>>(zp, wr_up, bup, zup);
    conv_head_mfma<<<dim3(32, 2, 4), dim3(512), 0, stream>>>(zup, wr_h, bh, out);
}